// Round 7
// baseline (573.898 us; speedup 1.0000x reference)
//
#include <hip/hip_runtime.h>

// ---------------- problem constants ----------------
#define N_WORDS 16384
#define MAXL    16
#define VOCABSZ 128
#define EMBD    64
#define HID     256
#define GATES   1024        // 4*HID
#define KTOT    320         // HID + EMBD (x folded into K)
#define AROW    328         // A row stride in shorts (656 B = 640 + 16 pad)
#define M_TILE  64          // words per workgroup
#define NT      256         // word tiles (N_WORDS / M_TILE)

typedef __attribute__((ext_vector_type(8))) short bf16x8;  // 8 bf16 = 4 VGPRs
typedef __attribute__((ext_vector_type(4))) float f32x4;
typedef __attribute__((ext_vector_type(4))) int   i32x4;

// ---------------- workspace layout (bytes) ----------------
// wsw : swizzled weights, A-fragment order: [dir][R 0..63][kk 0..9][lane 0..63][8 bf16]
#define OFF_WSW   0ul          // 2*64*10*64*16 = 1310720
#define OFF_EMB   1310720ul    // 128*64 bf16 = 16384
#define OFF_BIAS  1327104ul    // 2*1024 f32 = 8192 (interleaved unit-major: [4*unit+type])
#define OFF_SORT  1335296ul    // 16384 ints = 65536
// cell state lives in LDS (64 KB/block) -- no global c buffer

__device__ inline short tobf(float f) {           // fp32 -> bf16 RNE
  unsigned u = __float_as_uint(f);
  unsigned r = (u + 0x7fffu + ((u >> 16) & 1u)) >> 16;
  return (short)r;
}
// raw transcendental units via inline asm
__device__ inline float aexp2(float x) { float r; asm("v_exp_f32 %0, %1" : "=v"(r) : "v"(x)); return r; }
__device__ inline float arcp(float x)  { float r; asm("v_rcp_f32 %0, %1" : "=v"(r) : "v"(x)); return r; }
__device__ inline float fsig(float x)   { return arcp(1.0f + aexp2(x * -1.4426950408889634f)); }
__device__ inline float ftanhf(float x) { return 1.0f - 2.0f * arcp(1.0f + aexp2(x * 2.8853900817779268f)); }

// ---------------- fused prep: weight swizzle + emb/bias + length-sort (1 launch) --
__global__ void prep_all(const float* __restrict__ Wihf, const float* __restrict__ Whhf,
                         const float* __restrict__ Wihb, const float* __restrict__ Whhb,
                         const float* __restrict__ emb,
                         const float* __restrict__ bihf, const float* __restrict__ bhhf,
                         const float* __restrict__ bihb, const float* __restrict__ bhhb,
                         const int* __restrict__ lengths,
                         short* __restrict__ wsw, short* __restrict__ embw,
                         float* __restrict__ biasg, int* __restrict__ sorted) {
  __shared__ int hist[16], base[16], cnt[16];
  int blk = blockIdx.x;
  if (blk < 320) {
    int id = blk * 256 + threadIdx.x;            // 2*64*10*64 = 81920
    int d    = id / 40960;
    int r    = id % 40960;
    int R    = r / 640;
    int r2   = r % 640;
    int kk   = r2 / 64;
    int lane = r2 % 64;
    int m    = lane & 15;
    int unit = R * 4 + (m >> 2);
    int ty   = m & 3;
    int g    = ty * 256 + unit;
    int kb   = kk * 32 + (lane >> 4) * 8;
    const float* Wih = d ? Wihb : Wihf;
    const float* Whh = d ? Whhb : Whhf;
    bf16x8 v;
#pragma unroll
    for (int j = 0; j < 8; ++j) {
      int k = kb + j;
      float f = (k < HID) ? Whh[g * HID + k] : Wih[g * EMBD + (k - HID)];
      v[j] = tobf(f);
    }
    ((bf16x8*)wsw)[id] = v;
  } else if (blk < 360) {
    int id = (blk - 320) * 256 + threadIdx.x;    // 8192 + 2048 = 10240
    if (id < VOCABSZ * EMBD) {
      embw[id] = tobf(emb[id]);
    } else {
      int r = id - VOCABSZ * EMBD;
      if (r < 2048) {
        int d = r >> 10, n = r & 1023;
        int g = (n & 3) * 256 + (n >> 2);
        biasg[r] = d ? (bihb[g] + bhhb[g]) : (bihf[g] + bhhf[g]);
      }
    }
  } else {  // blk == 360: length-bucket sort, 256 threads (bin order arbitrary -- OK)
    int tid = threadIdx.x;
    if (tid < 16) { hist[tid] = 0; cnt[tid] = 0; }
    __syncthreads();
    for (int i = tid; i < N_WORDS; i += 256)
      atomicAdd(&hist[lengths[i] - 1], 1);
    __syncthreads();
    if (tid == 0) {
      int s = 0;
      for (int b = 0; b < 16; ++b) { base[b] = s; s += hist[b]; }
    }
    __syncthreads();
    for (int i = tid; i < N_WORDS; i += 256) {
      int b = lengths[i] - 1;
      int p = base[b] + atomicAdd(&cnt[b], 1);
      sorted[p] = i;
    }
  }
}

// ---------------- main fused BiLSTM kernel ----------------
// R7 structural change vs R6: DOUBLE-BUFFERED A (read h/x(t) from Ac, write
// h/x(t+1) to An) -> the mid-step snapshot barrier disappears, and the one
// remaining barrier per step is lgkm-only (raw asm): no cross-wave GLOBAL data
// exists, so vmcnt is never drained -- weight prefetch + embw gather stay in
// flight across step boundaries (T4 counted-vmcnt principle).
// Masking insight: a masked word's h/c are don't-care (its column only feeds
// its own gates; out is captured exactly at t==len-1; h2 in (-1,1), c bounded)
// -> always-write c2/h2, no freeze cndmasks, A[nxt] fully rewritten each step.
// NOTE (R4/R5 lessons): live set is at the 256-reg/wave edge; e is held only
// across the peeled last tile pair.
__global__ __launch_bounds__(512, 1) void lstm_main(
    const int* __restrict__ char_ids, const int* __restrict__ lengths,
    const short* __restrict__ wsw, const short* __restrict__ embw,
    const float* __restrict__ biasg, const int* __restrict__ sorted,
    float* __restrict__ out) {
  __shared__ __align__(16) short A0[M_TILE * AROW];  // [word][ h(256) | x(64) | pad(8) ]
  __shared__ __align__(16) short A1[M_TILE * AROW];
  __shared__ __align__(16) int   charl[M_TILE * 16];
  __shared__ __align__(16) float biasl[GATES];
  __shared__ __align__(16) f32x4 c4[8 * 8 * 64];     // [wv][rt][lane] cell state, 64 KB
  __shared__ int lenl[M_TILE];
  __shared__ int swl[M_TILE];

  const int tid  = threadIdx.x;
  const int lane = tid & 63;
  const int wv   = tid >> 6;            // 0..7
  const int quad = lane >> 4;
  const int colc = lane & 15;
  const int pb   = blockIdx.x;
  const int dir  = pb & 1;
  const int qb   = pb >> 1;
  const int tile = (qb & 1) ? (255 - (qb >> 1)) : (qb >> 1);

  if (tid < M_TILE) {
    int sw = sorted[tile * M_TILE + tid];
    swl[tid]  = sw;
    lenl[tid] = lengths[sw];
  }
  if (tid < 256) ((f32x4*)biasl)[tid] = ((const f32x4*)(biasg + dir * GATES))[tid];
  for (int i = tid; i < M_TILE * AROW / 2; i += 512) ((int*)A0)[i] = 0;    // h=0 init
  for (int i = tid; i < 8 * 8 * 64; i += 512) c4[i] = (f32x4){0.f, 0.f, 0.f, 0.f};
  __syncthreads();

  if (tid < 256) { // char ids for the tile (via sorted ids)
    int w = tid >> 2, ch = tid & 3;
    ((i32x4*)charl)[tid] = ((const i32x4*)(char_ids + swl[w] * 16))[ch];
  }
  int Lmax = lenl[lane];
  for (int o = 32; o; o >>= 1) { int v = __shfl_xor(Lmax, o, 64); Lmax = Lmax > v ? Lmax : v; }
  __syncthreads();  // charl ready

  // x staging: wave w covers words 8w..8w+7, 8 lanes/word; T14 split load/store
  const int xwl   = wv * 8 + (lane >> 3);
  const int xpart = lane & 7;
  auto x_load = [&](int tt) -> bf16x8 {
    int lw = lenl[xwl];
    int pos = (dir == 0) ? tt : (lw - 1 - tt);
    pos = pos < 0 ? 0 : (pos > 15 ? 15 : pos);
    int cid = charl[xwl * 16 + pos];
    return *(const bf16x8*)(embw + cid * EMBD + xpart * 8);
  };
  auto x_store = [&](short* An, bf16x8 e) {
    *(bf16x8*)(An + xwl * AROW + HID + xpart * 8) = e;
  };
  x_store(A0, x_load(0));

  // step-invariant lane constants (word dimension, per col-tile ct)
  int lenw[4], hadrb[4], oadr[4];
#pragma unroll
  for (int ct = 0; ct < 4; ++ct) {
    int wl = ct * 16 + colc;
    lenw[ct]  = lenl[wl];
    hadrb[ct] = wl * AROW + 32 * wv + quad;                  // + 4*rt : bf16 h slot
    oadr[ct]  = swl[wl] * 512 + dir * 256 + 32 * wv + quad;  // + 4*rt : fp32 out slot
  }
  const short* wp = wsw + ((size_t)dir * 64 + wv * 8) * 10 * 64 * 8 + lane * 8;
  f32x4* cptr = c4 + wv * (8 * 64) + lane;   // + rt*64

  __syncthreads();  // x(0) / zeros visible

  // preload rt=0 weight fragments once; ping-pong keeps them hot across steps
  bf16x8 wA[10], wB[10];
#pragma unroll
  for (int kk = 0; kk < 10; ++kk) wA[kk] = *(const bf16x8*)(wp + kk * 512);

  short* Ac = A0;   // read h(t), x(t)
  short* An = A1;   // write h(t+1), x(t+1)

#pragma unroll 1
  for (int t = 0; t < Lmax; ++t) {
    bf16x8 hx[4][10];  // B fragments: lane = B[k = kk*32 + quad*8 + j][n = ct*16 + colc]
#pragma unroll
    for (int ct = 0; ct < 4; ++ct)
#pragma unroll
      for (int kk = 0; kk < 10; ++kk)
        hx[ct][kk] = *(const bf16x8*)(Ac + (ct * 16 + colc) * AROW + kk * 32 + quad * 8);
    // no barrier: writes this step go to An, never to Ac

    auto wtile = [&](int rt, bf16x8(&wc)[10], bf16x8(&wn)[10], int pre) {
      // prefetch next row-tile's weight frags (pre=0 at rt=7 warms next step's rt0;
      // lgkm-only barrier keeps them in flight across the step boundary)
#pragma unroll
      for (int kk = 0; kk < 10; ++kk) wn[kk] = *(const bf16x8*)(wp + (pre * 10 + kk) * 512);
      f32x4 co4 = cptr[rt * 64];                 // LDS c, covered by the MFMA block
      // bias for lane's unit: one f32x4 = (b_i, b_f, b_g, b_o)
      f32x4 bias4 = *(const f32x4*)(biasl + 128 * wv + 16 * rt + 4 * quad);
      f32x4 acc[4];
#pragma unroll
      for (int ct = 0; ct < 4; ++ct) acc[ct] = bias4;
#pragma unroll
      for (int kk = 0; kk < 10; ++kk)
#pragma unroll
        for (int ct = 0; ct < 4; ++ct)  // 4 independent acc chains -> MFMA ILP
          acc[ct] = __builtin_amdgcn_mfma_f32_16x16x32_bf16(wc[kk], hx[ct][kk], acc[ct], 0, 0, 0);

      f32x4 cnew;
#pragma unroll
      for (int ct = 0; ct < 4; ++ct) {
        // lane-private epilogue: regs = i,f,g,o of (unit 32wv+4rt+quad, word ct*16+colc)
        // always-write: masked words' h/c are don't-care (bounded, never output)
        float ig = fsig(acc[ct][0]);
        float fg = fsig(acc[ct][1]);
        float gg = ftanhf(acc[ct][2]);
        float og = fsig(acc[ct][3]);
        float c2 = fg * co4[ct] + ig * gg;
        float h2 = og * ftanhf(c2);
        cnew[ct] = c2;
        An[hadrb[ct] + 4 * rt] = tobf(h2);
        if (t == lenw[ct] - 1) out[oadr[ct] + 4 * rt] = h2;  // final h in fp32
      }
      cptr[rt * 64] = cnew;   // one conflict-free ds_write_b128 (own slice, no hazard)
    };

#pragma unroll 1
    for (int rt2 = 0; rt2 < 6; rt2 += 2) {   // ping-pong weight buffers, static indices
      wtile(rt2,     wA, wB, rt2 + 1);
      wtile(rt2 + 1, wB, wA, rt2 + 2);
    }
    bf16x8 e = x_load(t + 1);   // global latency covered by tiles 6,7; e live 2 tiles
    wtile(6, wA, wB, 7);
    wtile(7, wB, wA, 0);        // prefetches next step's rt0 into wA
    x_store(An, e);

    // lgkm-only barrier: LDS writes (h/x/c) visible; vmem (weights, embw) stays
    // in flight across the step boundary. No global data crosses waves -> safe.
    asm volatile("s_waitcnt lgkmcnt(0)\n\ts_barrier" ::: "memory");
    short* tmp = Ac; Ac = An; An = tmp;
  }
}

// ---------------- launch ----------------
extern "C" void kernel_launch(void* const* d_in, const int* in_sizes, int n_in,
                              void* d_out, int out_size, void* d_ws, size_t ws_size,
                              hipStream_t stream) {
  const int*   char_ids = (const int*)d_in[0];
  const int*   lengths  = (const int*)d_in[1];
  const float* emb      = (const float*)d_in[2];
  const float* Wihf     = (const float*)d_in[3];
  const float* Whhf     = (const float*)d_in[4];
  const float* bihf     = (const float*)d_in[5];
  const float* bhhf     = (const float*)d_in[6];
  const float* Wihb     = (const float*)d_in[7];
  const float* Whhb     = (const float*)d_in[8];
  const float* bihb     = (const float*)d_in[9];
  const float* bhhb     = (const float*)d_in[10];

  char* ws = (char*)d_ws;
  short* wsw   = (short*)(ws + OFF_WSW);
  short* embw  = (short*)(ws + OFF_EMB);
  float* biasg = (float*)(ws + OFF_BIAS);
  int*   sortd = (int*)(ws + OFF_SORT);

  prep_all<<<361, 256, 0, stream>>>(Wihf, Whhf, Wihb, Whhb, emb,
                                    bihf, bhhf, bihb, bhhb, lengths,
                                    wsw, embw, biasg, sortd);
  lstm_main<<<512, 512, 0, stream>>>(char_ids, lengths, wsw, embw, biasg, sortd,
                                     (float*)d_out);
}

// Round 8
// 438.363 us; speedup vs baseline: 1.3092x; 1.3092x over previous
//
#include <hip/hip_runtime.h>

// ---------------- problem constants ----------------
#define N_WORDS 16384
#define MAXL    16
#define VOCABSZ 128
#define EMBD    64
#define HID     256
#define GATES   1024        // 4*HID
#define KTOT    320         // HID + EMBD (x folded into K)
#define AROW    328         // A row stride in shorts (656 B = 640 + 16 pad)
#define M_TILE  32          // words per workgroup (R8: halved -> 2 blocks/CU)
#define NT      512         // word tiles (N_WORDS / M_TILE)

typedef __attribute__((ext_vector_type(8))) short bf16x8;  // 8 bf16 = 4 VGPRs
typedef __attribute__((ext_vector_type(4))) float f32x4;
typedef __attribute__((ext_vector_type(2))) float f32x2;
typedef __attribute__((ext_vector_type(4))) int   i32x4;

// ---------------- workspace layout (bytes) ----------------
// wsw : swizzled weights, A-fragment order: [dir][R 0..63][kk 0..9][lane 0..63][8 bf16]
#define OFF_WSW   0ul          // 2*64*10*64*16 = 1310720
#define OFF_EMB   1310720ul    // 128*64 bf16 = 16384
#define OFF_BIAS  1327104ul    // 2*1024 f32 = 8192 (interleaved unit-major: [4*unit+type])
#define OFF_SORT  1335296ul    // 16384 ints = 65536
// cell state lives in LDS -- no global c buffer

__device__ inline short tobf(float f) {           // fp32 -> bf16 RNE
  unsigned u = __float_as_uint(f);
  unsigned r = (u + 0x7fffu + ((u >> 16) & 1u)) >> 16;
  return (short)r;
}
// raw transcendental units via inline asm
__device__ inline float aexp2(float x) { float r; asm("v_exp_f32 %0, %1" : "=v"(r) : "v"(x)); return r; }
__device__ inline float arcp(float x)  { float r; asm("v_rcp_f32 %0, %1" : "=v"(r) : "v"(x)); return r; }
__device__ inline float fsig(float x)   { return arcp(1.0f + aexp2(x * -1.4426950408889634f)); }
__device__ inline float ftanhf(float x) { return 1.0f - 2.0f * arcp(1.0f + aexp2(x * 2.8853900817779268f)); }

// ---------------- fused prep: weight swizzle + emb/bias + length-sort (1 launch) --
__global__ void prep_all(const float* __restrict__ Wihf, const float* __restrict__ Whhf,
                         const float* __restrict__ Wihb, const float* __restrict__ Whhb,
                         const float* __restrict__ emb,
                         const float* __restrict__ bihf, const float* __restrict__ bhhf,
                         const float* __restrict__ bihb, const float* __restrict__ bhhb,
                         const int* __restrict__ lengths,
                         short* __restrict__ wsw, short* __restrict__ embw,
                         float* __restrict__ biasg, int* __restrict__ sorted) {
  __shared__ int hist[16], base[16], cnt[16];
  int blk = blockIdx.x;
  if (blk < 320) {
    int id = blk * 256 + threadIdx.x;            // 2*64*10*64 = 81920
    int d    = id / 40960;
    int r    = id % 40960;
    int R    = r / 640;
    int r2   = r % 640;
    int kk   = r2 / 64;
    int lane = r2 % 64;
    int m    = lane & 15;
    int unit = R * 4 + (m >> 2);
    int ty   = m & 3;
    int g    = ty * 256 + unit;
    int kb   = kk * 32 + (lane >> 4) * 8;
    const float* Wih = d ? Wihb : Wihf;
    const float* Whh = d ? Whhb : Whhf;
    bf16x8 v;
#pragma unroll
    for (int j = 0; j < 8; ++j) {
      int k = kb + j;
      float f = (k < HID) ? Whh[g * HID + k] : Wih[g * EMBD + (k - HID)];
      v[j] = tobf(f);
    }
    ((bf16x8*)wsw)[id] = v;
  } else if (blk < 360) {
    int id = (blk - 320) * 256 + threadIdx.x;    // 8192 + 2048 = 10240
    if (id < VOCABSZ * EMBD) {
      embw[id] = tobf(emb[id]);
    } else {
      int r = id - VOCABSZ * EMBD;
      if (r < 2048) {
        int d = r >> 10, n = r & 1023;
        int g = (n & 3) * 256 + (n >> 2);
        biasg[r] = d ? (bihb[g] + bhhb[g]) : (bihf[g] + bhhf[g]);
      }
    }
  } else {  // blk == 360: length-bucket sort, 256 threads (bin order arbitrary -- OK)
    int tid = threadIdx.x;
    if (tid < 16) { hist[tid] = 0; cnt[tid] = 0; }
    __syncthreads();
    for (int i = tid; i < N_WORDS; i += 256)
      atomicAdd(&hist[lengths[i] - 1], 1);
    __syncthreads();
    if (tid == 0) {
      int s = 0;
      for (int b = 0; b < 16; ++b) { base[b] = s; s += hist[b]; }
    }
    __syncthreads();
    for (int i = tid; i < N_WORDS; i += 256) {
      int b = lengths[i] - 1;
      int p = base[b] + atomicAdd(&cnt[b], 1);
      sorted[p] = i;
    }
  }
}

// ---------------- main fused BiLSTM kernel ----------------
// R8 structural change vs R6: M_TILE 64 -> 32, 256 threads (4 waves), 2 blocks/CU.
// Same 8 waves/CU but from TWO INDEPENDENT blocks -> no shared barrier -> when one
// block is in barrier/epilogue, the other's waves feed the MFMA pipe (m114).
// Per-wave: 64 units (16 rt) x 32 words (2 ct): hx[2][10] = 80 regs (was 160) ->
// ~210 total, comfortably under the 256-reg 2-wave/SIMD cliff (R4/R5/R7 lesson).
// MFMA ILP: kk split into lo/hi halves -> 4 independent acc chains per wave.
// Cost accepted: weight L2 traffic doubles (reuse halves with M_TILE).
// Epilogue: always-write (masked words' h/c are bounded don't-cares; out is
// captured exactly at t==len-1 -- correctness proven by R7's passing run).
__global__ __launch_bounds__(256, 2) void lstm_main(
    const int* __restrict__ char_ids, const int* __restrict__ lengths,
    const short* __restrict__ wsw, const short* __restrict__ embw,
    const float* __restrict__ biasg, const int* __restrict__ sorted,
    float* __restrict__ out) {
  __shared__ __align__(16) short A[M_TILE * AROW];   // [word][ h(256) | x(64) | pad ] 21 KB
  __shared__ __align__(16) int   charl[M_TILE * 16]; // 2 KB
  __shared__ __align__(16) float biasl[GATES];       // 4 KB
  __shared__ __align__(8)  f32x2 c4[4 * 16 * 64];    // [wv][rt][lane] cell state, 32 KB
  __shared__ int lenl[M_TILE];
  __shared__ int swl[M_TILE];

  const int tid  = threadIdx.x;
  const int lane = tid & 63;
  const int wv   = tid >> 6;            // 0..3
  const int quad = lane >> 4;
  const int colc = lane & 15;
  const int pb   = blockIdx.x;
  const int dir  = pb & 1;
  const int qb   = pb >> 1;
  const int tile = (qb & 1) ? (511 - (qb >> 1)) : (qb >> 1);

  if (tid < M_TILE) {
    int sw = sorted[tile * M_TILE + tid];
    swl[tid]  = sw;
    lenl[tid] = lengths[sw];
  }
  ((f32x4*)biasl)[tid] = ((const f32x4*)(biasg + dir * GATES))[tid];
  for (int i = tid; i < M_TILE * AROW / 2; i += 256) ((int*)A)[i] = 0;     // h=0 init
  for (int i = tid; i < 4 * 16 * 64; i += 256) c4[i] = (f32x2){0.f, 0.f};
  __syncthreads();

  if (tid < 128) { // char ids for the tile (via sorted ids): 32 words x 16
    int w = tid >> 2, ch = tid & 3;
    ((i32x4*)charl)[tid] = ((const i32x4*)(char_ids + swl[w] * 16))[ch];
  }
  int Lmax = lenl[lane & 31];
  for (int o = 32; o; o >>= 1) { int v = __shfl_xor(Lmax, o, 64); Lmax = Lmax > v ? Lmax : v; }
  __syncthreads();  // charl ready

  // stage x for timestep tt into A cols [256,320): wave w covers words 8w..8w+7
  auto gather_x = [&](int tt) {
    int wl = wv * 8 + (lane >> 3);
    int part = lane & 7;
    int lw = lenl[wl];
    int pos = (dir == 0) ? tt : (lw - 1 - tt);
    pos = pos < 0 ? 0 : (pos > 15 ? 15 : pos);
    int cid = charl[wl * 16 + pos];
    bf16x8 e = *(const bf16x8*)(embw + cid * EMBD + part * 8);
    *(bf16x8*)(A + wl * AROW + HID + part * 8) = e;
  };
  gather_x(0);

  // step-invariant lane constants (word dimension, per col-tile ct)
  int lenw[2], hadrb[2], oadr[2];
#pragma unroll
  for (int ct = 0; ct < 2; ++ct) {
    int wl = ct * 16 + colc;
    lenw[ct]  = lenl[wl];
    hadrb[ct] = wl * AROW + 64 * wv + quad;                  // + 4*rt : bf16 h slot in A
    oadr[ct]  = swl[wl] * 512 + dir * 256 + 64 * wv + quad;  // + 4*rt : fp32 out slot
  }
  const short* wp = wsw + ((size_t)dir * 64 + wv * 16) * 10 * 64 * 8 + lane * 8;
  f32x2* cptr = c4 + wv * (16 * 64) + lane;   // + rt*64

  __syncthreads();  // x / zeros visible

  // preload rt=0 weight fragments once; ping-pong keeps them hot across steps
  bf16x8 wA[10], wB[10];
#pragma unroll
  for (int kk = 0; kk < 10; ++kk) wA[kk] = *(const bf16x8*)(wp + kk * 512);

#pragma unroll 1
  for (int t = 0; t < Lmax; ++t) {
    bf16x8 hx[2][10];  // B fragments: lane = B[k = kk*32 + quad*8 + j][n = ct*16 + colc]
#pragma unroll
    for (int ct = 0; ct < 2; ++ct)
#pragma unroll
      for (int kk = 0; kk < 10; ++kk)
        hx[ct][kk] = *(const bf16x8*)(A + (ct * 16 + colc) * AROW + kk * 32 + quad * 8);

    __syncthreads();  // all waves snapshotted A -> safe to overwrite h/x below

    auto wtile = [&](int rt, bf16x8(&wc)[10], bf16x8(&wn)[10], int pre) {
      // prefetch next row-tile's weight frags (pre=0 at rt=15 warms next step's rt0)
#pragma unroll
      for (int kk = 0; kk < 10; ++kk) wn[kk] = *(const bf16x8*)(wp + (pre * 10 + kk) * 512);
      f32x2 co2 = cptr[rt * 64];                 // LDS c, covered by the MFMA block
      // bias for lane's unit: one f32x4 = (b_i, b_f, b_g, b_o)
      f32x4 bias4 = *(const f32x4*)(biasl + 256 * wv + 16 * rt + 4 * quad);
      // kk split lo/hi -> 4 independent MFMA chains (ILP vs ~20cy MFMA latency)
      f32x4 aL[2], aH[2];
#pragma unroll
      for (int ct = 0; ct < 2; ++ct) { aL[ct] = bias4; aH[ct] = (f32x4){0.f,0.f,0.f,0.f}; }
#pragma unroll
      for (int kk = 0; kk < 5; ++kk)
#pragma unroll
        for (int ct = 0; ct < 2; ++ct) {
          aL[ct] = __builtin_amdgcn_mfma_f32_16x16x32_bf16(wc[kk],     hx[ct][kk],     aL[ct], 0, 0, 0);
          aH[ct] = __builtin_amdgcn_mfma_f32_16x16x32_bf16(wc[kk + 5], hx[ct][kk + 5], aH[ct], 0, 0, 0);
        }

      f32x2 cnew;
#pragma unroll
      for (int ct = 0; ct < 2; ++ct) {
        f32x4 acc = aL[ct] + aH[ct];
        // lane-private epilogue: regs = i,f,g,o of (unit 64wv+4rt+quad, word ct*16+colc)
        // always-write: masked words' h/c are don't-care (bounded, never output)
        float ig = fsig(acc[0]);
        float fg = fsig(acc[1]);
        float gg = ftanhf(acc[2]);
        float og = fsig(acc[3]);
        float c2 = fg * co2[ct] + ig * gg;
        float h2 = og * ftanhf(c2);
        cnew[ct] = c2;
        A[hadrb[ct] + 4 * rt] = tobf(h2);
        if (t == lenw[ct] - 1) out[oadr[ct] + 4 * rt] = h2;  // final h in fp32
      }
      cptr[rt * 64] = cnew;   // one ds_write_b64 (own slice, no hazard)
    };

#pragma unroll 1
    for (int rt2 = 0; rt2 < 16; rt2 += 2) {  // ping-pong weight buffers, static indices
      wtile(rt2,     wA, wB, rt2 + 1);
      wtile(rt2 + 1, wB, wA, (rt2 + 2) & 15); // rt=15 prefetches next step's rt0
    }

    gather_x(t + 1);   // x for next step (clamped; dead steps are masked)
    __syncthreads();   // h/x writes visible before next step's reads
  }
}

// ---------------- launch ----------------
extern "C" void kernel_launch(void* const* d_in, const int* in_sizes, int n_in,
                              void* d_out, int out_size, void* d_ws, size_t ws_size,
                              hipStream_t stream) {
  const int*   char_ids = (const int*)d_in[0];
  const int*   lengths  = (const int*)d_in[1];
  const float* emb      = (const float*)d_in[2];
  const float* Wihf     = (const float*)d_in[3];
  const float* Whhf     = (const float*)d_in[4];
  const float* bihf     = (const float*)d_in[5];
  const float* bhhf     = (const float*)d_in[6];
  const float* Wihb     = (const float*)d_in[7];
  const float* Whhb     = (const float*)d_in[8];
  const float* bihb     = (const float*)d_in[9];
  const float* bhhb     = (const float*)d_in[10];

  char* ws = (char*)d_ws;
  short* wsw   = (short*)(ws + OFF_WSW);
  short* embw  = (short*)(ws + OFF_EMB);
  float* biasg = (float*)(ws + OFF_BIAS);
  int*   sortd = (int*)(ws + OFF_SORT);

  prep_all<<<361, 256, 0, stream>>>(Wihf, Whhf, Wihb, Whhb, emb,
                                    bihf, bhhf, bihb, bhhb, lengths,
                                    wsw, embw, biasg, sortd);
  lstm_main<<<1024, 256, 0, stream>>>(char_ids, lengths, wsw, embw, biasg, sortd,
                                      (float*)d_out);
}